// Round 10
// baseline (381.302 us; speedup 1.0000x reference)
//
#include <hip/hip_runtime.h>
#include <stdint.h>

// Self-attention, B=8, S=2048, D=1024, fp32 in/out, bf16 MFMA compute.
//
// Pipeline:
//   1. k_cvt: x -> xb (bf16), zero l;  k_cvt3: Wq/Wk/Wv -> Wb
//   2. k_qkv3 (z=0,1): Q/K = xb @ W^T + b   (z=2): Vt = (xb @ Wv^T + bv)^T
//   3. k_scores: U = exp((Q @ K^T)/32) bf16 + atomic per-row sums into l
//   4. k_pv   : Out[b][sq][d] from C^T = Vt @ U^T, scaled 1/l[sq] (float4)
//
// R14 = R9 loop (best: 38% MfmaUtil, qkv 118us) restructured to the m201
// template phase shape -- NO invented scheduling:
//  (a) ALL sched_barrier(0) removed (m141: order-pinning defeats the
//      compiler scheduler; they were never ablated -- R11/R12's failures
//      were sched_barrier-heavy).
//  (b) 2 barriers per 16-MFMA phase (template pacing):
//      [reads][stage] BAR prio1 16xMFMA prio0 BAR  -- per phase.
//  (c) stage split 2+2: phase A stages A-halves of tile t+3, phase B stages
//      B-halves + vmcnt(8). Outstanding at vmcnt = tiles t+2,t+3 = 8 loads,
//      identical accounting to R9 (tail vmcnt(4)/vmcnt(0) branches same).
//  Safety unchanged from R9 (refcheck'd x3): stage targets buf[(t+3)&3] =
//  buf[(t-1)&3]; tile t-1's last reads complete before its phase-B MFMA
//  lgkm-wait, >=1 barrier before any tile-t stage issues. Reads of tile t
//  occur after t-1's closing barrier which followed vmcnt confirming tile t.
//  Kept: ring-4 x K32, XOR chunk swizzle (conflicts 524K ~ free), pv
//  transposed EPI2 (refcheck'd R11/R12), batch<->XCD pinning, z-slowest
//  W-pinning, l zeroed in k_cvt, exp-sum softmax (|s|<=|q||k|/32).
//
// ws layout:
//   [0,       33.5M)  Q        16384x1024 bf16
//   [33.5M,   67.1M)  K        16384x1024 bf16
//   [67.1M,  100.7M)  Vt       8 x 1024x2048 bf16
//   [100.7M, 167.8M)  U        8 x 2048x2048 bf16  (first half aliases xb)
//   [167.8M, 174.1M)  Wb       3 x 1024x1024 bf16
//   [174.1M, ...)     l        16384 fp32 (attn row sums, atomic)

typedef __bf16 bf16_t;
typedef __bf16 bf16x8 __attribute__((ext_vector_type(8)));
typedef __bf16 bf16x4 __attribute__((ext_vector_type(4)));
typedef float f32x4 __attribute__((ext_vector_type(4)));

__device__ __forceinline__ void gload_lds16(const bf16_t* g, bf16_t* l) {
    __builtin_amdgcn_global_load_lds((const __attribute__((address_space(1))) void*)g,
                                     (__attribute__((address_space(3))) void*)l,
                                     16, 0, 0);
}

// ---------------------------------------------------------------------------
// Core GEMM: C[M,N] = A[M,K] @ B[N,K]^T, bf16 row-major K-contiguous.
// Tile 256x256, BK=32, 512 threads (8 waves 2Mx4N), per-wave 8x4 16x16x32
// MFMA fragments (output 128x64 per wave).
// lds: caller-provided 65536 bf16 (128 KiB): 4 ring buffers of 16384 elems
// (A tile 8192 + B tile 8192). Epilogue (EPI 0/1) reuses it as 128x264 repack.
// EPI: 0 = (+bias[col]) -> bf16 coalesced stores
//      1 = exp(acc*scale) -> bf16 stores + atomic row sums into aux
//      2 = acc*(1/aux[col]) -> fp32 float4 stores to Cf[col*ldc + row]
//      3 = (+bias[col]) -> bf16 TRANSPOSED into Vt[b][col][row]
// ---------------------------------------------------------------------------
template <int EPI, int LDA, int LDB>
__device__ __forceinline__ void gemm256_core(
    bf16_t* __restrict__ lds,
    const bf16_t* __restrict__ A,
    const bf16_t* __restrict__ B,
    bf16_t* __restrict__ Cb, float* __restrict__ Cf, int ldc,
    float* __restrict__ aux, float scale, int K,
    int m0, int n0)
{
    const int t    = threadIdx.x;         // 0..511
    const int lane = t & 63;
    const int wave = t >> 6;              // 0..7
    const int wm   = wave >> 2;           // 0..1  (M half)
    const int wn   = wave & 3;            // 0..3  (N quarter)
    const int lr   = lane & 15;
    const int quad = lane >> 4;

    // Staging: thread t owns 16B slots {t, 512+t} of each tile half.
    // Physical slot s of row r holds logical chunk s ^ ((r>>1)&3) -- the
    // inverse of the read-side XOR (involution), so reads see linear data.
    const int rowS = t >> 2;                       // 0..127
    const int qS   = (t & 3) ^ ((rowS >> 1) & 3);
    const bf16_t* Ag = A + (size_t)(m0 + rowS) * LDA + qS * 8;
    const bf16_t* Bg = B + (size_t)(n0 + rowS) * LDB + qS * 8;
    const int dst0 = t * 8;                        // elems

    // Fragment read offsets (elems): row-major 256x32, slot XOR-swizzled by
    // (lr>>1)&3 -> per-16-lane-quarter start classes (row&1)*4 + slot cover
    // all 8 classes twice -> 2-way bank aliasing only (free).
    const int ko   = (quad ^ ((lr >> 1) & 3)) * 8;
    const int aoff = (wm * 128 + lr) * 32 + ko;
    const int boff = (wn * 64 + lr) * 32 + ko;

    f32x4 acc[8][4];
#pragma unroll
    for (int i = 0; i < 8; i++)
#pragma unroll
        for (int j = 0; j < 4; j++) acc[i][j] = (f32x4){0.f, 0.f, 0.f, 0.f};

    const int T = K >> 5;   // K32-steps (>= 4)

    // Prologue: stage tiles 0,1,2 (12 loads/thread), then require tile 0.
#pragma unroll
    for (int tt = 0; tt < 3; ++tt) {
        bf16_t* Ab = lds + tt * 16384;
        bf16_t* Bb = Ab + 8192;
        const int kt = tt * 32;
        gload_lds16(Ag + kt,                     Ab + dst0);
        gload_lds16(Ag + kt + (size_t)128 * LDA, Ab + 4096 + dst0);
        gload_lds16(Bg + kt,                     Bb + dst0);
        gload_lds16(Bg + kt + (size_t)128 * LDB, Bb + 4096 + dst0);
    }
    asm volatile("s_waitcnt vmcnt(8)" ::: "memory");
    __builtin_amdgcn_s_barrier();

    for (int tk = 0; tk < T; ++tk) {
        const bf16_t* Ab = lds + (tk & 3) * 16384;
        const bf16_t* Bb = Ab + 8192;
        bf16x8 af[8], bfr[4];
        // ==== phase A: read 8 frags, stage A-halves of t+3, BAR, MFMA, BAR
#pragma unroll
        for (int j = 0; j < 4; ++j)
            bfr[j] = *(const bf16x8*)(Bb + boff + 512 * j);
#pragma unroll
        for (int i = 0; i < 4; ++i)
            af[i] = *(const bf16x8*)(Ab + aoff + 512 * i);
        if (tk + 3 < T) {
            bf16_t* An = lds + ((tk + 3) & 3) * 16384;   // buf of dead tile t-1
            const int kt = (tk + 3) * 32;
            gload_lds16(Ag + kt,                     An + dst0);
            gload_lds16(Ag + kt + (size_t)128 * LDA, An + 4096 + dst0);
        }
        __builtin_amdgcn_s_barrier();
        __builtin_amdgcn_s_setprio(1);
#pragma unroll
        for (int i = 0; i < 4; ++i)
#pragma unroll
            for (int j = 0; j < 4; ++j)
                acc[i][j] = __builtin_amdgcn_mfma_f32_16x16x32_bf16(af[i], bfr[j], acc[i][j], 0, 0, 0);
        __builtin_amdgcn_s_setprio(0);
        __builtin_amdgcn_s_barrier();
        // ==== phase B: read 4 frags, stage B-halves of t+3, vmcnt, BAR, MFMA, BAR
#pragma unroll
        for (int i = 4; i < 8; ++i)
            af[i] = *(const bf16x8*)(Ab + aoff + 512 * i);
        if (tk + 3 < T) {
            bf16_t* Bn = lds + ((tk + 3) & 3) * 16384 + 8192;
            const int kt = (tk + 3) * 32;
            gload_lds16(Bg + kt,                     Bn + dst0);
            gload_lds16(Bg + kt + (size_t)128 * LDB, Bn + 4096 + dst0);
            asm volatile("s_waitcnt vmcnt(8)" ::: "memory");   // tile t+1 landed
        } else if (tk + 2 < T) {
            asm volatile("s_waitcnt vmcnt(4)" ::: "memory");
        } else {
            asm volatile("s_waitcnt vmcnt(0)" ::: "memory");
        }
        __builtin_amdgcn_s_barrier();
        __builtin_amdgcn_s_setprio(1);
#pragma unroll
        for (int i = 4; i < 8; ++i)
#pragma unroll
            for (int j = 0; j < 4; ++j)
                acc[i][j] = __builtin_amdgcn_mfma_f32_16x16x32_bf16(af[i], bfr[j], acc[i][j], 0, 0, 0);
        __builtin_amdgcn_s_setprio(0);
        __builtin_amdgcn_s_barrier();
    }

    // Epilogue. C/D frag layout: col = lane&15, row = quad*4 + reg.
    if (EPI == 0 || EPI == 1) {
        // Repack half-by-half (wm half h -> 128x256) in LDS (stride 264),
        // then coalesced 16B stores; EPI1 also accumulates row sums.
#pragma unroll
        for (int h = 0; h < 2; ++h) {
            __syncthreads();
            if (wm == h) {
#pragma unroll
                for (int j = 0; j < 4; ++j) {
                    const int col = wn * 64 + j * 16 + lr;
                    const float bv = (EPI == 0) ? aux[n0 + col] : 0.f;
#pragma unroll
                    for (int i = 0; i < 8; ++i) {
                        const int row = i * 16 + quad * 4;
#pragma unroll
                        for (int r = 0; r < 4; ++r) {
                            float v = (EPI == 0) ? (acc[i][j][r] + bv)
                                                 : __expf(acc[i][j][r] * scale);
                            lds[(row + r) * 264 + col] = (__bf16)v;
                        }
                    }
                }
            }
            __syncthreads();
            const int r2 = t >> 2;            // 0..127
            const int c0 = (t & 3) * 8;       // interleaved col chunks
            float part = 0.f;
#pragma unroll
            for (int c = 0; c < 8; ++c) {
                bf16x8 v = *(const bf16x8*)(lds + r2 * 264 + c0 + c * 32);
                *(bf16x8*)(Cb + (size_t)(m0 + h * 128 + r2) * ldc + n0 + c0 + c * 32) = v;
                if (EPI == 1) {
#pragma unroll
                    for (int e = 0; e < 8; ++e) part += (float)v[e];
                }
            }
            if (EPI == 1) {
                part += __shfl_xor(part, 1);
                part += __shfl_xor(part, 2);
                if ((t & 3) == 0) atomicAdd(aux + m0 + h * 128 + r2, part);
            }
        }
    } else if (EPI == 2) {
        // Transposed consumer: C fragment (row,col) -> Cf[col*ldc + row];
        // the 4 acc regs (r) are row-consecutive -> one float4 store.
#pragma unroll
        for (int j = 0; j < 4; ++j) {
            const int col = n0 + wn * 64 + j * 16 + lr;
            const float s = 1.0f / aux[col];
            float* ccol = Cf + (size_t)col * ldc + m0 + wm * 128;
#pragma unroll
            for (int i = 0; i < 8; ++i) {
                f32x4 v = acc[i][j];
                v[0] *= s; v[1] *= s; v[2] *= s; v[3] *= s;
                *(f32x4*)(ccol + i * 16 + quad * 4) = v;
            }
        }
    } else {
        // EPI 3: transposed write into Vt[b][col][row], rows global = b*2048+s
#pragma unroll
        for (int j = 0; j < 4; ++j) {
            const int col = n0 + wn * 64 + j * 16 + lr;      // d index
            const float bv = aux[col];
#pragma unroll
            for (int i = 0; i < 8; ++i) {
                const int rowg = m0 + wm * 128 + i * 16 + quad * 4;  // global s
                const int b    = rowg >> 11;
                const int s    = rowg & 2047;
                bf16x4 p = { (__bf16)(acc[i][j][0] + bv), (__bf16)(acc[i][j][1] + bv),
                             (__bf16)(acc[i][j][2] + bv), (__bf16)(acc[i][j][3] + bv) };
                *(bf16x4*)(Cb + ((size_t)b << 21) + ((size_t)col << 11) + s) = p;
            }
        }
    }
}

// --------------------------- kernel wrappers -------------------------------

// Q/K/Vt projection, grid (8,96) = 768 blocks. xcd = lid&7; within an XCD,
// x' (weight n-tile, 4) fast, y' (A-strip, 8) middle, z' (matrix) slowest
// -> W_z (2 MB) L2-pinned per phase.
__global__ __launch_bounds__(512, 1) void k_qkv3(
    const bf16_t* __restrict__ xb, const bf16_t* __restrict__ Wb,
    bf16_t* __restrict__ Q, bf16_t* __restrict__ Vt,
    const float* __restrict__ bq, const float* __restrict__ bk,
    const float* __restrict__ bv)
{
    __shared__ bf16_t lds[65536];
    const int lid  = blockIdx.x + 8 * blockIdx.y;
    const int xcd  = lid & 7;
    const int slot = lid >> 3;          // 0..95
    const int z    = slot >> 5;         // 0..2, slowest
    const int rem  = slot & 31;
    const int xt   = rem & 3;           // fast (4 n-tiles)
    const int yt   = xcd * 8 + (rem >> 2);
    if (z < 2) {
        float* bias = (float*)((z == 0) ? bq : bk);
        gemm256_core<0, 1024, 1024>(lds, xb, Wb + (size_t)z * 1048576,
                                    Q + (size_t)z * 16777216, nullptr, 1024,
                                    bias, 0.f, 1024, yt * 256, xt * 256);
    } else {
        gemm256_core<3, 1024, 1024>(lds, xb, Wb + (size_t)2 * 1048576,
                                    Vt, nullptr, 0,
                                    (float*)bv, 0.f, 1024, yt * 256, xt * 256);
    }
}

// scores, grid (8,64) = 512 blocks: batch = lid&7 == XCD -> per-XCD working
// set is one batch's K matrix (4 MB = L2). x-tile fast.
__global__ __launch_bounds__(512, 1) void k_scores(
    const bf16_t* __restrict__ Q, const bf16_t* __restrict__ Km,
    bf16_t* __restrict__ U, float* __restrict__ l)
{
    __shared__ bf16_t lds[65536];
    const int lid = blockIdx.x + 8 * blockIdx.y;
    const int b   = lid & 7;
    const int si  = lid >> 3;           // 0..63
    const int xt  = si & 7;
    const int yt  = si >> 3;
    gemm256_core<1, 1024, 1024>(lds, Q + (size_t)b * 2048 * 1024,
                                Km + (size_t)b * 2048 * 1024,
                                U + (size_t)b * 2048 * 2048, nullptr, 2048,
                                l + b * 2048, 0.03125f, 1024,
                                yt * 256, xt * 256);
}

// PV transposed, grid (8,32) = 256 blocks: C^T[d][sq] = Vt[b] @ U[b]^T,
// A = Vt (M=1024 d-rows, LDA=2048), B = U (N=2048 sq-rows, LDB=2048),
// K = 2048 (sk). Out[b][sq][d] gets coalesced float4 stores, scale 1/l[sq].
// batch = lid&7 == XCD.
__global__ __launch_bounds__(512, 1) void k_pv(
    const bf16_t* __restrict__ U, const bf16_t* __restrict__ Vt,
    float* __restrict__ Out, float* __restrict__ l)
{
    __shared__ bf16_t lds[65536];
    const int lid = blockIdx.x + 8 * blockIdx.y;
    const int b   = lid & 7;
    const int si  = lid >> 3;           // 0..31
    const int xt  = si & 7;             // sq tile (8)
    const int yt  = si >> 3;            // d tile  (4)
    gemm256_core<2, 2048, 2048>(lds, Vt + ((size_t)b << 21),
                                U + (size_t)b * 2048 * 2048,
                                nullptr, Out + (size_t)b * 2048 * 1024, 1024,
                                l + b * 2048, 0.f, 2048,
                                yt * 256, xt * 256);
}

// fp32 -> bf16 conversion, 4 elems/thread; also zeroes l (16384 floats)
__global__ __launch_bounds__(256) void k_cvt(
    const float* __restrict__ in, bf16_t* __restrict__ out, long ngroups,
    float* __restrict__ l)
{
    long idx    = (long)blockIdx.x * blockDim.x + threadIdx.x;
    long stride = (long)gridDim.x * blockDim.x;
    if (blockIdx.x < 64) l[blockIdx.x * 256 + threadIdx.x] = 0.f;
    for (long i = idx; i < ngroups; i += stride) {
        float4 v = ((const float4*)in)[i];
        bf16x4 o = { (__bf16)v.x, (__bf16)v.y, (__bf16)v.z, (__bf16)v.w };
        ((bf16x4*)out)[i] = o;
    }
}

// fused 3-weight fp32 -> bf16 (z selects source)
__global__ __launch_bounds__(256) void k_cvt3(
    const float* __restrict__ w0, const float* __restrict__ w1,
    const float* __restrict__ w2, bf16_t* __restrict__ out)
{
    const int z = blockIdx.z;
    const float* in = (z == 0) ? w0 : (z == 1) ? w1 : w2;
    bf16_t* o = out + (size_t)z * 1048576;
    long i = (long)blockIdx.x * blockDim.x + threadIdx.x;
    float4 v = ((const float4*)in)[i];
    bf16x4 ov = { (__bf16)v.x, (__bf16)v.y, (__bf16)v.z, (__bf16)v.w };
    ((bf16x4*)o)[i] = ov;
}

// ---------------------------------------------------------------------------

extern "C" void kernel_launch(void* const* d_in, const int* in_sizes, int n_in,
                              void* d_out, int out_size, void* d_ws, size_t ws_size,
                              hipStream_t stream)
{
    const float* x  = (const float*)d_in[0];
    const float* Wq = (const float*)d_in[1];
    const float* bq = (const float*)d_in[2];
    const float* Wk = (const float*)d_in[3];
    const float* bk = (const float*)d_in[4];
    const float* Wv = (const float*)d_in[5];
    const float* bv = (const float*)d_in[6];

    bf16_t* Q    = (bf16_t*)d_ws;              // 16384x1024
    bf16_t* Km   = Q + 16777216;               // 16384x1024
    bf16_t* Vt   = Km + 16777216;              // 8 x 1024x2048
    bf16_t* U    = Vt + 16777216;              // 8 x 2048x2048
    bf16_t* xb   = U;                          // alias: dead before U written
    bf16_t* Wb   = U + 33554432;               // 3 x 1024x1024
    float*  l    = (float*)(Wb + 3145728);     // 16384

    k_cvt<<<dim3(2048), 256, 0, stream>>>(x, xb, 16777216 / 4, l);
    k_cvt3<<<dim3(1024, 1, 3), 256, 0, stream>>>(Wq, Wk, Wv, Wb);
    k_qkv3<<<dim3(8, 96), 512, 0, stream>>>(xb, Wb, Q, Vt, bq, bk, bv);
    k_scores<<<dim3(8, 64), 512, 0, stream>>>(Q, Km, U, l);
    k_pv<<<dim3(8, 32), 512, 0, stream>>>(U, Vt, (float*)d_out, l);
}

// Round 11
// 369.655 us; speedup vs baseline: 1.0315x; 1.0315x over previous
//
#include <hip/hip_runtime.h>
#include <stdint.h>

// Self-attention, B=8, S=2048, D=1024, fp32 in/out, bf16 MFMA compute.
//
// Pipeline:
//   1. k_cvt: x -> xb (bf16), zero l;  k_cvt3: Wq/Wk/Wv -> Wb
//   2. k_qkv3 (z=0,1): Q/K = xb @ W^T + b   (z=2): Vt = (xb @ Wv^T + bv)^T
//   3. k_scores: U = exp((Q @ K^T)/32) bf16 + atomic per-row sums into l
//   4. k_pv   : Out[b][sq][d] from C^T = Vt @ U^T, scaled 1/l[sq] (float4)
//
// R15: BK=64 / ring-2 / ONE barrier per K64 (guide's minimum-2-phase recipe).
//  Post-mortem R11/R12/R14: every hand-scheduled variant of the BK=32 core
//  lost to compiler-scheduled R9 (34-38% MfmaUtil band). Cycle model: per
//  K64, R9 pays 4 barriers + 2 vmcnt events (~2x the MFMA floor in stall).
//  This core: stage(t+1) 8 gloads FIRST (latency hides under 64 MFMAs),
//  then 24 ds_reads + 64 MFMA as ONE compiler-scheduled region, then
//  vmcnt(0) (~free: issued >1200cy earlier) + barrier. 64 MFMA/barrier
//  (AITER-class density) vs R9's 16.
//  - LDS 128KB = ring-2 x (A 256x64 + B 256x64). 128B rows would be 32-way
//    bank conflicts -> XOR swizzle chunk^=(row&7) (8x16B slots/row, full
//    involution, both sides): read classes 8 distinct x 2 lanes = 2-way
//    (free, m136). Stage src stays 128B-coalesced (permuted within row).
//  - Ring-2 safety, 1 barrier/iter: stage(t+1) writes the buffer whose
//    (t-1) reads all completed before the previous iteration's barrier;
//    vmcnt(0) before barrier publishes tile t+1 to all waves.
//  Kept: pv-transposed EPI2, batch<->XCD pinning, z-slowest W-pinning,
//  l zeroed in k_cvt, exp-sum softmax (|s|<=|q||k|/32), epilogues verbatim.
//
// ws layout:
//   [0,       33.5M)  Q        16384x1024 bf16
//   [33.5M,   67.1M)  K        16384x1024 bf16
//   [67.1M,  100.7M)  Vt       8 x 1024x2048 bf16
//   [100.7M, 167.8M)  U        8 x 2048x2048 bf16  (first half aliases xb)
//   [167.8M, 174.1M)  Wb       3 x 1024x1024 bf16
//   [174.1M, ...)     l        16384 fp32 (attn row sums, atomic)

typedef __bf16 bf16_t;
typedef __bf16 bf16x8 __attribute__((ext_vector_type(8)));
typedef __bf16 bf16x4 __attribute__((ext_vector_type(4)));
typedef float f32x4 __attribute__((ext_vector_type(4)));

__device__ __forceinline__ void gload_lds16(const bf16_t* g, bf16_t* l) {
    __builtin_amdgcn_global_load_lds((const __attribute__((address_space(1))) void*)g,
                                     (__attribute__((address_space(3))) void*)l,
                                     16, 0, 0);
}

// ---------------------------------------------------------------------------
// Core GEMM: C[M,N] = A[M,K] @ B[N,K]^T, bf16 row-major K-contiguous.
// Tile 256x256, BK=64, 512 threads (8 waves 2Mx4N), per-wave 8x4 16x16x32
// MFMA fragments x 2 K-halves = 64 MFMA per K64 iteration.
// lds: caller-provided 65536 bf16 (128 KiB) = ring-2 x 32768 (A 16384 +
// B 16384). Epilogue (EPI 0/1) reuses it as 128x264 repack.
// Per-row layout: 8 chunks of 8 elems; phys slot s holds chunk s^(row&7).
// EPI: 0 = (+bias[col]) -> bf16 coalesced stores
//      1 = exp(acc*scale) -> bf16 stores + atomic row sums into aux
//      2 = acc*(1/aux[col]) -> fp32 float4 stores to Cf[col*ldc + row]
//      3 = (+bias[col]) -> bf16 TRANSPOSED into Vt[b][col][row]
// ---------------------------------------------------------------------------
template <int EPI, int LDA, int LDB>
__device__ __forceinline__ void gemm256_core(
    bf16_t* __restrict__ lds,
    const bf16_t* __restrict__ A,
    const bf16_t* __restrict__ B,
    bf16_t* __restrict__ Cb, float* __restrict__ Cf, int ldc,
    float* __restrict__ aux, float scale, int K,
    int m0, int n0)
{
    const int th   = threadIdx.x;         // 0..511
    const int lane = th & 63;
    const int wave = th >> 6;             // 0..7
    const int wm   = wave >> 2;           // 0..1  (M half)
    const int wn   = wave & 3;            // 0..3  (N quarter)
    const int lr   = lane & 15;
    const int quad = lane >> 4;
    const int lr7  = lr & 7;

    // Staging: 4 loads per matrix per thread. Load l covers row l*64 + rS,
    // phys slot th&7, which must hold logical chunk (th&7)^(row&7); row&7 ==
    // rS&7 for all l (l*64 = 0 mod 8). Per wave+load: 8 rows x 128B
    // contiguous (chunk-permuted within the row) -> fully coalesced.
    const int rS = th >> 3;                        // 0..63
    const int cS = (th & 7) ^ (rS & 7);            // logical chunk
    const bf16_t* Ag = A + (size_t)(m0 + rS) * LDA + cS * 8;
    const bf16_t* Bg = B + (size_t)(n0 + rS) * LDB + cS * 8;
    const int dstS = th * 8;                       // elems

    // Fragment reads: af[i] row = wm*128+i*16+lr (row&7 == lr7); K-chunk
    // kk*4+quad at phys slot (kk*4+quad)^lr7. Per 16-lane group: classes
    // (lr&7 xor) cover all 8 slots twice -> 2-way only.
    const int arow = (wm * 128 + lr) * 64;
    const int brow = (wn * 64 + lr) * 64;

    f32x4 acc[8][4];
#pragma unroll
    for (int i = 0; i < 8; i++)
#pragma unroll
        for (int j = 0; j < 4; j++) acc[i][j] = (f32x4){0.f, 0.f, 0.f, 0.f};

    const int T = K >> 6;   // K64 iterations (>= 2)

    // Prologue: stage tile 0 into buf0, drain, barrier.
#pragma unroll
    for (int l = 0; l < 4; ++l) {
        gload_lds16(Ag + (size_t)(l * 64) * LDA, lds + l * 4096 + dstS);
        gload_lds16(Bg + (size_t)(l * 64) * LDB, lds + 16384 + l * 4096 + dstS);
    }
    asm volatile("s_waitcnt vmcnt(0)" ::: "memory");
    __builtin_amdgcn_s_barrier();

    for (int tk = 0; tk < T; ++tk) {
        bf16_t* cur = lds + (tk & 1) * 32768;
        bf16_t* oth = lds + ((tk + 1) & 1) * 32768;
        // stage tile t+1 first: HBM latency hides under the 64 MFMAs below
        if (tk + 1 < T) {
            const int kt = (tk + 1) * 64;
#pragma unroll
            for (int l = 0; l < 4; ++l) {
                gload_lds16(Ag + kt + (size_t)(l * 64) * LDA, oth + l * 4096 + dstS);
                gload_lds16(Bg + kt + (size_t)(l * 64) * LDB, oth + 16384 + l * 4096 + dstS);
            }
        }
        // one compiler-scheduled region: 24 ds_reads + 64 MFMA
#pragma unroll
        for (int kk = 0; kk < 2; ++kk) {
            const int ko = ((kk * 4 + quad) ^ lr7) * 8;
            bf16x8 af[8], bfr[4];
#pragma unroll
            for (int j = 0; j < 4; ++j)
                bfr[j] = *(const bf16x8*)(cur + 16384 + brow + j * 1024 + ko);
#pragma unroll
            for (int i = 0; i < 8; ++i)
                af[i] = *(const bf16x8*)(cur + arow + i * 1024 + ko);
            __builtin_amdgcn_s_setprio(1);
#pragma unroll
            for (int i = 0; i < 8; ++i)
#pragma unroll
                for (int j = 0; j < 4; ++j)
                    acc[i][j] = __builtin_amdgcn_mfma_f32_16x16x32_bf16(af[i], bfr[j], acc[i][j], 0, 0, 0);
            __builtin_amdgcn_s_setprio(0);
        }
        asm volatile("s_waitcnt vmcnt(0)" ::: "memory");   // tile t+1 landed (~free)
        __builtin_amdgcn_s_barrier();                      // publish + protect cur
    }

    // Epilogue. C/D frag layout: col = lane&15, row = quad*4 + reg.
    if (EPI == 0 || EPI == 1) {
        // Repack half-by-half (wm half h -> 128x256) in LDS (stride 264),
        // then coalesced 16B stores; EPI1 also accumulates row sums.
#pragma unroll
        for (int h = 0; h < 2; ++h) {
            __syncthreads();
            if (wm == h) {
#pragma unroll
                for (int j = 0; j < 4; ++j) {
                    const int col = wn * 64 + j * 16 + lr;
                    const float bv = (EPI == 0) ? aux[n0 + col] : 0.f;
#pragma unroll
                    for (int i = 0; i < 8; ++i) {
                        const int row = i * 16 + quad * 4;
#pragma unroll
                        for (int r = 0; r < 4; ++r) {
                            float v = (EPI == 0) ? (acc[i][j][r] + bv)
                                                 : __expf(acc[i][j][r] * scale);
                            lds[(row + r) * 264 + col] = (__bf16)v;
                        }
                    }
                }
            }
            __syncthreads();
            const int r2 = th >> 2;           // 0..127
            const int c0 = (th & 3) * 8;      // interleaved col chunks
            float part = 0.f;
#pragma unroll
            for (int c = 0; c < 8; ++c) {
                bf16x8 v = *(const bf16x8*)(lds + r2 * 264 + c0 + c * 32);
                *(bf16x8*)(Cb + (size_t)(m0 + h * 128 + r2) * ldc + n0 + c0 + c * 32) = v;
                if (EPI == 1) {
#pragma unroll
                    for (int e = 0; e < 8; ++e) part += (float)v[e];
                }
            }
            if (EPI == 1) {
                part += __shfl_xor(part, 1);
                part += __shfl_xor(part, 2);
                if ((th & 3) == 0) atomicAdd(aux + m0 + h * 128 + r2, part);
            }
        }
    } else if (EPI == 2) {
        // Transposed consumer: C fragment (row,col) -> Cf[col*ldc + row];
        // the 4 acc regs (r) are row-consecutive -> one float4 store.
#pragma unroll
        for (int j = 0; j < 4; ++j) {
            const int col = n0 + wn * 64 + j * 16 + lr;
            const float s = 1.0f / aux[col];
            float* ccol = Cf + (size_t)col * ldc + m0 + wm * 128;
#pragma unroll
            for (int i = 0; i < 8; ++i) {
                f32x4 v = acc[i][j];
                v[0] *= s; v[1] *= s; v[2] *= s; v[3] *= s;
                *(f32x4*)(ccol + i * 16 + quad * 4) = v;
            }
        }
    } else {
        // EPI 3: transposed write into Vt[b][col][row], rows global = b*2048+s
#pragma unroll
        for (int j = 0; j < 4; ++j) {
            const int col = n0 + wn * 64 + j * 16 + lr;      // d index
            const float bv = aux[col];
#pragma unroll
            for (int i = 0; i < 8; ++i) {
                const int rowg = m0 + wm * 128 + i * 16 + quad * 4;  // global s
                const int b    = rowg >> 11;
                const int s    = rowg & 2047;
                bf16x4 p = { (__bf16)(acc[i][j][0] + bv), (__bf16)(acc[i][j][1] + bv),
                             (__bf16)(acc[i][j][2] + bv), (__bf16)(acc[i][j][3] + bv) };
                *(bf16x4*)(Cb + ((size_t)b << 21) + ((size_t)col << 11) + s) = p;
            }
        }
    }
}

// --------------------------- kernel wrappers -------------------------------

// Q/K/Vt projection, grid (8,96) = 768 blocks. xcd = lid&7; within an XCD,
// x' (weight n-tile, 4) fast, y' (A-strip, 8) middle, z' (matrix) slowest
// -> W_z (2 MB) L2-pinned per phase.
__global__ __launch_bounds__(512, 1) void k_qkv3(
    const bf16_t* __restrict__ xb, const bf16_t* __restrict__ Wb,
    bf16_t* __restrict__ Q, bf16_t* __restrict__ Vt,
    const float* __restrict__ bq, const float* __restrict__ bk,
    const float* __restrict__ bv)
{
    __shared__ bf16_t lds[65536];
    const int lid  = blockIdx.x + 8 * blockIdx.y;
    const int xcd  = lid & 7;
    const int slot = lid >> 3;          // 0..95
    const int z    = slot >> 5;         // 0..2, slowest
    const int rem  = slot & 31;
    const int xt   = rem & 3;           // fast (4 n-tiles)
    const int yt   = xcd * 8 + (rem >> 2);
    if (z < 2) {
        float* bias = (float*)((z == 0) ? bq : bk);
        gemm256_core<0, 1024, 1024>(lds, xb, Wb + (size_t)z * 1048576,
                                    Q + (size_t)z * 16777216, nullptr, 1024,
                                    bias, 0.f, 1024, yt * 256, xt * 256);
    } else {
        gemm256_core<3, 1024, 1024>(lds, xb, Wb + (size_t)2 * 1048576,
                                    Vt, nullptr, 0,
                                    (float*)bv, 0.f, 1024, yt * 256, xt * 256);
    }
}

// scores, grid (8,64) = 512 blocks: batch = lid&7 == XCD -> per-XCD working
// set is one batch's K matrix (4 MB = L2). x-tile fast.
__global__ __launch_bounds__(512, 1) void k_scores(
    const bf16_t* __restrict__ Q, const bf16_t* __restrict__ Km,
    bf16_t* __restrict__ U, float* __restrict__ l)
{
    __shared__ bf16_t lds[65536];
    const int lid = blockIdx.x + 8 * blockIdx.y;
    const int b   = lid & 7;
    const int si  = lid >> 3;           // 0..63
    const int xt  = si & 7;
    const int yt  = si >> 3;
    gemm256_core<1, 1024, 1024>(lds, Q + (size_t)b * 2048 * 1024,
                                Km + (size_t)b * 2048 * 1024,
                                U + (size_t)b * 2048 * 2048, nullptr, 2048,
                                l + b * 2048, 0.03125f, 1024,
                                yt * 256, xt * 256);
}

// PV transposed, grid (8,32) = 256 blocks: C^T[d][sq] = Vt[b] @ U[b]^T,
// A = Vt (M=1024 d-rows, LDA=2048), B = U (N=2048 sq-rows, LDB=2048),
// K = 2048 (sk). Out[b][sq][d] gets coalesced float4 stores, scale 1/l[sq].
// batch = lid&7 == XCD.
__global__ __launch_bounds__(512, 1) void k_pv(
    const bf16_t* __restrict__ U, const bf16_t* __restrict__ Vt,
    float* __restrict__ Out, float* __restrict__ l)
{
    __shared__ bf16_t lds[65536];
    const int lid = blockIdx.x + 8 * blockIdx.y;
    const int b   = lid & 7;
    const int si  = lid >> 3;           // 0..31
    const int xt  = si & 7;             // sq tile (8)
    const int yt  = si >> 3;            // d tile  (4)
    gemm256_core<2, 2048, 2048>(lds, Vt + ((size_t)b << 21),
                                U + (size_t)b * 2048 * 2048,
                                nullptr, Out + (size_t)b * 2048 * 1024, 1024,
                                l + b * 2048, 0.f, 2048,
                                yt * 256, xt * 256);
}

// fp32 -> bf16 conversion, 4 elems/thread; also zeroes l (16384 floats)
__global__ __launch_bounds__(256) void k_cvt(
    const float* __restrict__ in, bf16_t* __restrict__ out, long ngroups,
    float* __restrict__ l)
{
    long idx    = (long)blockIdx.x * blockDim.x + threadIdx.x;
    long stride = (long)gridDim.x * blockDim.x;
    if (blockIdx.x < 64) l[blockIdx.x * 256 + threadIdx.x] = 0.f;
    for (long i = idx; i < ngroups; i += stride) {
        float4 v = ((const float4*)in)[i];
        bf16x4 o = { (__bf16)v.x, (__bf16)v.y, (__bf16)v.z, (__bf16)v.w };
        ((bf16x4*)out)[i] = o;
    }
}

// fused 3-weight fp32 -> bf16 (z selects source)
__global__ __launch_bounds__(256) void k_cvt3(
    const float* __restrict__ w0, const float* __restrict__ w1,
    const float* __restrict__ w2, bf16_t* __restrict__ out)
{
    const int z = blockIdx.z;
    const float* in = (z == 0) ? w0 : (z == 1) ? w1 : w2;
    bf16_t* o = out + (size_t)z * 1048576;
    long i = (long)blockIdx.x * blockDim.x + threadIdx.x;
    float4 v = ((const float4*)in)[i];
    bf16x4 ov = { (__bf16)v.x, (__bf16)v.y, (__bf16)v.z, (__bf16)v.w };
    ((bf16x4*)o)[i] = ov;
}

// ---------------------------------------------------------------------------

extern "C" void kernel_launch(void* const* d_in, const int* in_sizes, int n_in,
                              void* d_out, int out_size, void* d_ws, size_t ws_size,
                              hipStream_t stream)
{
    const float* x  = (const float*)d_in[0];
    const float* Wq = (const float*)d_in[1];
    const float* bq = (const float*)d_in[2];
    const float* Wk = (const float*)d_in[3];
    const float* bk = (const float*)d_in[4];
    const float* Wv = (const float*)d_in[5];
    const float* bv = (const float*)d_in[6];

    bf16_t* Q    = (bf16_t*)d_ws;              // 16384x1024
    bf16_t* Km   = Q + 16777216;               // 16384x1024
    bf16_t* Vt   = Km + 16777216;              // 8 x 1024x2048
    bf16_t* U    = Vt + 16777216;              // 8 x 2048x2048
    bf16_t* xb   = U;                          // alias: dead before U written
    bf16_t* Wb   = U + 33554432;               // 3 x 1024x1024
    float*  l    = (float*)(Wb + 3145728);     // 16384

    k_cvt<<<dim3(2048), 256, 0, stream>>>(x, xb, 16777216 / 4, l);
    k_cvt3<<<dim3(1024, 1, 3), 256, 0, stream>>>(Wq, Wk, Wv, Wb);
    k_qkv3<<<dim3(8, 96), 512, 0, stream>>>(xb, Wb, Q, Vt, bq, bk, bv);
    k_scores<<<dim3(8, 64), 512, 0, stream>>>(Q, Km, U, l);
    k_pv<<<dim3(8, 32), 512, 0, stream>>>(U, Vt, (float*)d_out, l);
}